// Round 4
// baseline (237.428 us; speedup 1.0000x reference)
//
#include <hip/hip_runtime.h>

#define N_NODES 50000
#define FEAT    64
#define HID     128
#define N_EDGES 640000
#define NBLK    196            // scanperm blocks (all co-resident)
#define GCAP    64             // per-node staged index capacity

typedef __attribute__((ext_vector_type(8))) short bf16x8;
typedef __attribute__((ext_vector_type(4))) float f32x4;

static __device__ __forceinline__ unsigned short f2bf(float f) {
    unsigned u = __float_as_uint(f);
    u = u + 0x7fffu + ((u >> 16) & 1u);          // RNE
    return (unsigned short)(u >> 16);
}
static __device__ __forceinline__ float bflo(unsigned u) {
    return __uint_as_float(u << 16);
}
static __device__ __forceinline__ float bfhi(unsigned u) {
    return __uint_as_float(u & 0xffff0000u);
}

// unpack one uint4 (8 bf16 feats) into 8 f32 accumulators
#define ACC8(A, v) { \
    A[0] += bflo((v).x); A[1] += bfhi((v).x); \
    A[2] += bflo((v).y); A[3] += bfhi((v).y); \
    A[4] += bflo((v).z); A[5] += bfhi((v).z); \
    A[6] += bflo((v).w); A[7] += bfhi((v).w); }

// async global->LDS, 16 B per lane. Global addr is PER-LANE; LDS dest is
// wave-uniform base + lane*16 (m104). No dest register -> the register
// allocator cannot de-pipeline it; vmcnt counts it; we wait with counted
// inline-asm waits (T4).
typedef __attribute__((address_space(1))) const void glob_void;
typedef __attribute__((address_space(3))) void lds_void;
static __device__ __forceinline__ void gload16(const void* g, void* l) {
    __builtin_amdgcn_global_load_lds((glob_void*)g, (lds_void*)l, 16, 0, 0);
}

// all-atomic monotone-generation grid barrier (device-scope -> cross-XCD safe)
static __device__ __forceinline__ void gridbar(int* bar, int gen) {
    __syncthreads();
    if (threadIdx.x == 0) {
        __threadfence();
        int arrived = atomicAdd(&bar[0], 1);
        if (arrived == NBLK - 1) {
            atomicExch(&bar[0], 0);
            __threadfence();
            atomicExch(&bar[1], gen);
        } else {
            while (atomicAdd(&bar[1], 0) < gen) __builtin_amdgcn_s_sleep(2);
        }
        __threadfence();
    }
    __syncthreads();
}

// ---- hist (records per-edge slot -> fill needs no atomics) + bf16 cvt -----
// also zeroes the pad row (index N_NODES) of emb_bf and hbf: gather loops pad
// neighbor lists with this row so no masks/tails are needed.
__global__ __launch_bounds__(256) void histcvt_kernel(
        const int* __restrict__ dst, const float* __restrict__ emb,
        const float* __restrict__ W1l, const float* __restrict__ W1r,
        const float* __restrict__ W2l, const float* __restrict__ W2r,
        int* __restrict__ count, int* __restrict__ eslot,
        unsigned* __restrict__ emb_bf_u, unsigned* __restrict__ Wbf_u,
        unsigned* __restrict__ hbf_u) {
    int gtid = blockIdx.x * 256 + threadIdx.x;
    if (gtid < N_EDGES) {
        int slot = atomicAdd(&count[dst[gtid]], 1);
        eslot[gtid] = slot;
    }
    for (int i = gtid; i < N_NODES * FEAT / 2; i += N_EDGES) {
        float2 v = ((const float2*)emb)[i];
        emb_bf_u[i] = ((unsigned)f2bf(v.y) << 16) | (unsigned)f2bf(v.x);
    }
    if (gtid < FEAT / 2) emb_bf_u[N_NODES * FEAT / 2 + gtid] = 0u;  // zero pad row
    if (gtid < HID / 2)  hbf_u[N_NODES * HID / 2 + gtid]   = 0u;    // zero pad row
    if (gtid < 24576) {                      // 49152 weight elems, paired
        int w = gtid * 2;
        float lo, hi;
        if (w < 8192)       { lo = W1l[w];         hi = W1l[w + 1]; }
        else if (w < 16384) { lo = W1r[w - 8192];  hi = W1r[w - 8191]; }
        else if (w < 32768) { lo = W2l[w - 16384]; hi = W2l[w - 16383]; }
        else                { lo = W2r[w - 32768]; hi = W2r[w - 32767]; }
        Wbf_u[gtid] = ((unsigned)f2bf(hi) << 16) | (unsigned)f2bf(lo);
    }
}

// ---- fused node-level scans + degree-sort permutation (196 blocks) --------
// perm is written in DESCENDING degree order: longest gather blocks are
// dispatched first in the fgemm kernels -> no slow-straggler drain tail.
__global__ __launch_bounds__(256) void scanperm_kernel(
        const int* __restrict__ count, int* offset, int* dhist, int* dcur,
        int* bsum, int* boff, int* dstart, int* perm, int* bar) {
    __shared__ int tmp[256];
    __shared__ int lh[64];
    __shared__ int lb2[64];
    int t = threadIdx.x;
    int gtid = blockIdx.x * 256 + t;

    {   // phase 0: per-block scan of count + degree histogram
        if (t < 64) lh[t] = 0;
        int v = (gtid < N_NODES) ? count[gtid] : 0;
        tmp[t] = v;
        __syncthreads();
        if (gtid < N_NODES) atomicAdd(&lh[v < 63 ? v : 63], 1);
        for (int off = 1; off < 256; off <<= 1) {
            int add = (t >= off) ? tmp[t - off] : 0;
            __syncthreads();
            tmp[t] += add;
            __syncthreads();
        }
        if (gtid < N_NODES) offset[gtid] = tmp[t] - v;
        if (t == 255) bsum[blockIdx.x] = tmp[255];
        if (t < 64 && lh[t] > 0) atomicAdd(&dhist[t], lh[t]);
    }
    gridbar(bar, 1);

    // phase 1: scan block sums (block 0) + degree starts (block 1)
    if (blockIdx.x < 2) {
        const int* in  = (blockIdx.x == 0) ? bsum : dhist;
        int*       out = (blockIdx.x == 0) ? boff : dstart;
        int cnt        = (blockIdx.x == 0) ? NBLK : 64;
        int v = (t < cnt) ? in[t] : 0;
        tmp[t] = v;
        __syncthreads();
        for (int off = 1; off < 256; off <<= 1) {
            int add = (t >= off) ? tmp[t - off] : 0;
            __syncthreads();
            tmp[t] += add;
            __syncthreads();
        }
        if (t < cnt) out[t] = tmp[t] - v;
    }
    gridbar(bar, 2);

    // phase 2: offset fixup + degree-sorted permutation (reversed: descending)
    if (gtid < N_NODES) offset[gtid] += boff[blockIdx.x];
    if (gtid == 0) offset[N_NODES] = N_EDGES;
    {
        if (t < 64) lh[t] = 0;
        __syncthreads();
        int d = 0, slot = 0;
        if (gtid < N_NODES) {
            int c = count[gtid];
            d = c < 63 ? c : 63;
            slot = atomicAdd(&lh[d], 1);
        }
        __syncthreads();
        if (t < 64 && lh[t] > 0) lb2[t] = atomicAdd(&dcur[t], lh[t]);
        __syncthreads();
        if (gtid < N_NODES)
            perm[(N_NODES - 1) - (dstart[d] + lb2[d] + slot)] = gtid;
    }
}

// ---- CSR fill: atomic-free (slot precomputed in histcvt) ------------------
__global__ void fill_kernel(const int* __restrict__ src, const int* __restrict__ dst,
                            const int* __restrict__ offset,
                            const int* __restrict__ eslot, int* __restrict__ esrc) {
    int e = blockIdx.x * blockDim.x + threadIdx.x;
    if (e >= N_EDGES) return;
    esrc[offset[dst[e]] + eslot[e]] = src[e];
}

// ---- fused layer 1: async-LDS gather-mean + dual MFMA GEMM + relu ---------
// block = 16 perm-consecutive nodes, 4 waves, each wave owns 4 subgroups.
// GATHER via global_load_lds: one instr stages 2 rows (128 B each) for all 4
// subs of the wave (64 lanes x 16 B -> 1 KB slab). Window = 4 instrs = 8
// rows/sub; double-buffered; steady-state s_waitcnt vmcnt(4) (never 0
// mid-list). Fire-and-forget: no dest registers -> regalloc cannot
// de-pipeline (rounds 0-3: every register-level pipeline collapsed to 44
// VGPR / one batch in flight).
__global__ __launch_bounds__(256, 4) void fgemm1_kernel(
        const unsigned short* __restrict__ embb, const int* __restrict__ offset,
        const int* __restrict__ esrc, const int* __restrict__ perm,
        const short* __restrict__ Wl, const short* __restrict__ Wr,
        const float* __restrict__ bias, unsigned short* __restrict__ hout) {
    __shared__ unsigned short smean[16][72];   // 64 used + 8 pad
    __shared__ int sidx[16][GCAP];
    __shared__ int nid[16];
    __shared__ uint4 stg[4][2][4][4][2][8];    // wave,buf,instr,subloc,half,fo: 32 KB
    int t = threadIdx.x;
    if (t < 16) nid[t] = perm[blockIdx.x * 16 + t];
    __syncthreads();

    int sub = t >> 4, fl = t & 15;
    int w = t >> 6;
    int subloc = sub & 3;
    int half = (t >> 3) & 1, fo = t & 7;
    int n = nid[sub];
    int beg = offset[n], deg = offset[n + 1] - beg;
    int degw = deg;                            // wave-max degree (uniform per 16)
    degw = max(degw, __shfl_xor(degw, 16));
    degw = max(degw, __shfl_xor(degw, 32));
    float acc[8] = {0,0,0,0,0,0,0,0};
    const uint4* eb4 = (const uint4*)embb;     // 8 uint4 per 64-feat row

    if (degw <= GCAP) {                        // wave-uniform fast path
        int rrw = (degw + 7) & ~7;             // rows padded to x8 (wave-uniform)
        for (int j = fl; j < rrw; j += 16)     // pad with zero row N_NODES
            sidx[sub][j] = (j < deg) ? esrc[beg + j] : N_NODES;
        int nw = rrw >> 3;                     // 8-row windows

#define ISSUE1(k, buf) { \
        int rb = (k) * 8; \
        _Pragma("unroll") \
        for (int j = 0; j < 4; ++j) { \
            const uint4* g = eb4 + (size_t)sidx[(w<<2) + subloc][rb + j*2 + half] * 8 + fo; \
            gload16(g, &stg[w][buf][j][0][0][0]); \
        } }
#define CONSUME1(buf) { \
        _Pragma("unroll") \
        for (int j = 0; j < 4; ++j) { \
            uint4 v = stg[w][buf][j][subloc][half][fo]; \
            ACC8(acc, v) \
        } }

        if (nw > 0) {
            ISSUE1(0, 0)
            if (nw > 1) ISSUE1(1, 1)
            for (int k = 0; k < nw; ++k) {
                if (k < nw - 1) { asm volatile("s_waitcnt vmcnt(4)" ::: "memory"); }
                else            { asm volatile("s_waitcnt vmcnt(0)" ::: "memory"); }
                __builtin_amdgcn_sched_barrier(0);
                if (k & 1) { CONSUME1(1) } else { CONSUME1(0) }
                if (k + 2 < nw) {
                    asm volatile("s_waitcnt lgkmcnt(0)" ::: "memory");
                    __builtin_amdgcn_sched_barrier(0);
                    if (k & 1) { ISSUE1(k + 2, 1) } else { ISSUE1(k + 2, 0) }
                }
            }
        }
#undef ISSUE1
#undef CONSUME1
    } else {                                   // rare slow path (deg > GCAP)
        for (int i = half; i < deg; i += 2) {
            uint4 v = eb4[(size_t)esrc[beg + i] * 8 + fo];
            ACC8(acc, v)
        }
    }
    float dinv = 1.0f / fmaxf((float)deg, 1.0f);
    unsigned ow[4];
    #pragma unroll
    for (int k = 0; k < 4; ++k) {
        float lo = acc[2 * k];     lo += __shfl_xor(lo, 8);
        float hi = acc[2 * k + 1]; hi += __shfl_xor(hi, 8);
        ow[k] = ((unsigned)f2bf(hi * dinv) << 16) | (unsigned)f2bf(lo * dinv);
    }
    if (half == 0) {
        uint4 o4 = {ow[0], ow[1], ow[2], ow[3]};
        *(uint4*)&smean[sub][fo * 8] = o4;
    }
    __syncthreads();

    int wave = t >> 6, lane = t & 63;
    int col = lane & 15, quad = lane >> 4;
    int ncol = nid[col];
    int nt0 = wave * 2, nt1 = nt0 + 1;
    f32x4 acc0 = (f32x4){0.f,0.f,0.f,0.f}, acc1 = (f32x4){0.f,0.f,0.f,0.f};
    #pragma unroll
    for (int kb = 0; kb < FEAT; kb += 32) {
        bf16x8 am = *(const bf16x8*)&smean[col][kb + quad * 8];
        bf16x8 ax = *(const bf16x8*)(embb + (size_t)ncol * FEAT + kb + quad * 8);
        bf16x8 bl0 = *(const bf16x8*)(Wl + (nt0 * 16 + col) * FEAT + kb + quad * 8);
        bf16x8 br0 = *(const bf16x8*)(Wr + (nt0 * 16 + col) * FEAT + kb + quad * 8);
        bf16x8 bl1 = *(const bf16x8*)(Wl + (nt1 * 16 + col) * FEAT + kb + quad * 8);
        bf16x8 br1 = *(const bf16x8*)(Wr + (nt1 * 16 + col) * FEAT + kb + quad * 8);
        acc0 = __builtin_amdgcn_mfma_f32_16x16x32_bf16(am, bl0, acc0, 0, 0, 0);
        acc0 = __builtin_amdgcn_mfma_f32_16x16x32_bf16(ax, br0, acc0, 0, 0, 0);
        acc1 = __builtin_amdgcn_mfma_f32_16x16x32_bf16(am, bl1, acc1, 0, 0, 0);
        acc1 = __builtin_amdgcn_mfma_f32_16x16x32_bf16(ax, br1, acc1, 0, 0, 0);
    }
    float bv0 = bias[nt0 * 16 + col];
    float bv1 = bias[nt1 * 16 + col];
    #pragma unroll
    for (int r = 0; r < 4; ++r) {
        int node = nid[quad * 4 + r];
        hout[(size_t)node * HID + nt0 * 16 + col] = f2bf(fmaxf(acc0[r] + bv0, 0.f));
        hout[(size_t)node * HID + nt1 * 16 + col] = f2bf(fmaxf(acc1[r] + bv1, 0.f));
    }
}

// ---- fused layer 2: async-LDS gather-mean + dual MFMA GEMM ----------------
// Rows 256 B = 16 x 16 B. One global_load_lds stages row i for all 4 subs of
// the wave (64 lanes x 16 B). Window = 4 instrs = 4 rows/sub, double-buffered;
// steady-state vmcnt(4). smean row stride 272 B (2-way alias = free).
__global__ __launch_bounds__(256, 4) void fgemm2_kernel(
        const unsigned short* __restrict__ hbf, const int* __restrict__ offset,
        const int* __restrict__ esrc, const int* __restrict__ perm,
        const short* __restrict__ Wl, const short* __restrict__ Wr,
        const float* __restrict__ bias, float* __restrict__ out) {
    __shared__ unsigned short smean[16][136];  // 128 used + 8 pad
    __shared__ int sidx[16][GCAP];
    __shared__ int nid[16];
    __shared__ uint4 stg[4][2][4][4][16];      // wave,buf,instr,subloc,fl: 32 KB
    int t = threadIdx.x;
    if (t < 16) nid[t] = perm[blockIdx.x * 16 + t];
    __syncthreads();

    int sub = t >> 4, fl = t & 15;
    int w = t >> 6;
    int subloc = sub & 3;
    int n = nid[sub];
    int beg = offset[n], deg = offset[n + 1] - beg;
    int degw = deg;
    degw = max(degw, __shfl_xor(degw, 16));
    degw = max(degw, __shfl_xor(degw, 32));
    float acc[8] = {0,0,0,0,0,0,0,0};
    const uint4* hb4 = (const uint4*)hbf;      // 16 uint4 per 128-feat row

    if (degw <= GCAP) {                        // wave-uniform fast path
        int rrw = (degw + 3) & ~3;             // rows padded to x4 (wave-uniform)
        for (int j = fl; j < rrw; j += 16)
            sidx[sub][j] = (j < deg) ? esrc[beg + j] : N_NODES;
        int nw = rrw >> 2;                     // 4-row windows

#define ISSUE2(k, buf) { \
        int rb = (k) * 4; \
        _Pragma("unroll") \
        for (int j = 0; j < 4; ++j) { \
            const uint4* g = hb4 + (size_t)sidx[(w<<2) + subloc][rb + j] * 16 + fl; \
            gload16(g, &stg[w][buf][j][0][0]); \
        } }
#define CONSUME2(buf) { \
        _Pragma("unroll") \
        for (int j = 0; j < 4; ++j) { \
            uint4 v = stg[w][buf][j][subloc][fl]; \
            ACC8(acc, v) \
        } }

        if (nw > 0) {
            ISSUE2(0, 0)
            if (nw > 1) ISSUE2(1, 1)
            for (int k = 0; k < nw; ++k) {
                if (k < nw - 1) { asm volatile("s_waitcnt vmcnt(4)" ::: "memory"); }
                else            { asm volatile("s_waitcnt vmcnt(0)" ::: "memory"); }
                __builtin_amdgcn_sched_barrier(0);
                if (k & 1) { CONSUME2(1) } else { CONSUME2(0) }
                if (k + 2 < nw) {
                    asm volatile("s_waitcnt lgkmcnt(0)" ::: "memory");
                    __builtin_amdgcn_sched_barrier(0);
                    if (k & 1) { ISSUE2(k + 2, 1) } else { ISSUE2(k + 2, 0) }
                }
            }
        }
#undef ISSUE2
#undef CONSUME2
    } else {                                   // rare slow path (deg > GCAP)
        for (int i = 0; i < deg; ++i) {
            uint4 v = hb4[(size_t)esrc[beg + i] * 16 + fl];
            ACC8(acc, v)
        }
    }
    float dinv = 1.0f / fmaxf((float)deg, 1.0f);
    unsigned ow[4];
    #pragma unroll
    for (int k = 0; k < 4; ++k) {
        float lo = acc[2 * k] * dinv;
        float hi = acc[2 * k + 1] * dinv;
        ow[k] = ((unsigned)f2bf(hi) << 16) | (unsigned)f2bf(lo);
    }
    uint4 o4 = {ow[0], ow[1], ow[2], ow[3]};
    *(uint4*)&smean[sub][fl * 8] = o4;
    __syncthreads();

    int wave = t >> 6, lane = t & 63;
    int col = lane & 15, quad = lane >> 4;
    int ncol = nid[col];
    int nt0 = wave * 2, nt1 = nt0 + 1;
    f32x4 acc0 = (f32x4){0.f,0.f,0.f,0.f}, acc1 = (f32x4){0.f,0.f,0.f,0.f};
    #pragma unroll
    for (int kb = 0; kb < HID; kb += 32) {
        bf16x8 am = *(const bf16x8*)&smean[col][kb + quad * 8];
        bf16x8 ax = *(const bf16x8*)(hbf + (size_t)ncol * HID + kb + quad * 8);
        bf16x8 bl0 = *(const bf16x8*)(Wl + (nt0 * 16 + col) * HID + kb + quad * 8);
        bf16x8 br0 = *(const bf16x8*)(Wr + (nt0 * 16 + col) * HID + kb + quad * 8);
        bf16x8 bl1 = *(const bf16x8*)(Wl + (nt1 * 16 + col) * HID + kb + quad * 8);
        bf16x8 br1 = *(const bf16x8*)(Wr + (nt1 * 16 + col) * HID + kb + quad * 8);
        acc0 = __builtin_amdgcn_mfma_f32_16x16x32_bf16(am, bl0, acc0, 0, 0, 0);
        acc0 = __builtin_amdgcn_mfma_f32_16x16x32_bf16(ax, br0, acc0, 0, 0, 0);
        acc1 = __builtin_amdgcn_mfma_f32_16x16x32_bf16(am, bl1, acc1, 0, 0, 0);
        acc1 = __builtin_amdgcn_mfma_f32_16x16x32_bf16(ax, br1, acc1, 0, 0, 0);
    }
    float bv0 = bias[nt0 * 16 + col];
    float bv1 = bias[nt1 * 16 + col];
    #pragma unroll
    for (int r = 0; r < 4; ++r) {
        int node = nid[quad * 4 + r];
        out[(size_t)node * HID + nt0 * 16 + col] = acc0[r] + bv0;
        out[(size_t)node * HID + nt1 * 16 + col] = acc1[r] + bv1;
    }
}

extern "C" void kernel_launch(void* const* d_in, const int* in_sizes, int n_in,
                              void* d_out, int out_size, void* d_ws, size_t ws_size,
                              hipStream_t stream) {
    const int*   edge_index = (const int*)d_in[0];
    const float* emb        = (const float*)d_in[1];
    const float* W1l        = (const float*)d_in[2];
    const float* b1l        = (const float*)d_in[3];
    const float* W1r        = (const float*)d_in[4];
    const float* W2l        = (const float*)d_in[5];
    const float* b2l        = (const float*)d_in[6];
    const float* W2r        = (const float*)d_in[7];
    float* out = (float*)d_out;

    const int* src = edge_index;
    const int* dst = edge_index + N_EDGES;

    // ws layout (int-indexed; bf16 regions 16B-aligned), ~25 MB.
    // count..bar = one contiguous zeroed run [50004, 100136).
    // emb_bf / hbf each carry one extra ZERO pad row at node index N_NODES.
    int* iws    = (int*)d_ws;
    int* offset = iws;                        // 50001 (pad to 50004)
    int* count  = iws + 50004;                // 50000 (zeroed)
    int* dhist  = iws + 100004;               // 64 (zeroed)
    int* dcur   = iws + 100068;               // 64 (zeroed)
    int* bar    = iws + 100132;               // 4 (zeroed)
    int* bsum   = iws + 100136;               // 256
    int* boff   = iws + 100392;               // 256
    int* dstart = iws + 100648;               // 64
    int* perm   = iws + 100712;               // 50000
    int* esrc   = iws + 150712;               // 640000 -> 790712
    int* eslot  = iws + 790712;               // 640000 -> 1430712
    unsigned short* W1l_bf = (unsigned short*)(iws + 1430712);  // 8192 bf16
    unsigned short* W1r_bf = (unsigned short*)(iws + 1434808);  // 8192
    unsigned short* W2l_bf = (unsigned short*)(iws + 1438904);  // 16384
    unsigned short* W2r_bf = (unsigned short*)(iws + 1447096);  // 16384
    unsigned short* Wbf    = W1l_bf;                            // contiguous 49152
    unsigned short* emb_bf = (unsigned short*)(iws + 1455288);  // 50001*64 bf16
    unsigned short* hbf    = (unsigned short*)(iws + 3055320);  // 50001*128 bf16

    (void)hipMemsetAsync(count, 0, (size_t)(100136 - 50004) * sizeof(int), stream);

    histcvt_kernel<<<(N_EDGES + 255) / 256, 256, 0, stream>>>(
        dst, emb, W1l, W1r, W2l, W2r, count, eslot,
        (unsigned*)emb_bf, (unsigned*)Wbf, (unsigned*)hbf);
    scanperm_kernel<<<NBLK, 256, 0, stream>>>(
        count, offset, dhist, dcur, bsum, boff, dstart, perm, bar);
    fill_kernel<<<(N_EDGES + 255) / 256, 256, 0, stream>>>(
        src, dst, offset, eslot, esrc);

    fgemm1_kernel<<<N_NODES / 16, 256, 0, stream>>>(
        emb_bf, offset, esrc, perm,
        (const short*)W1l_bf, (const short*)W1r_bf, b1l, hbf);
    fgemm2_kernel<<<N_NODES / 16, 256, 0, stream>>>(
        hbf, offset, esrc, perm,
        (const short*)W2l_bf, (const short*)W2r_bf, b2l, out);
}